// Round 4
// baseline (1683.640 us; speedup 1.0000x reference)
//
#include <hip/hip_runtime.h>
#include <math.h>

// ReNet: 4 LSTMs (vertical ud/du over patch columns, horizontal lr/rl over
// rows of the vertical output). fp32, no fp32 MFMA on CDNA4 -> packed-fp32
// VALU (v_pk_fma_f32 via __builtin_elementwise_fma on float2).
//
// Decomposition (both kernels): thread (dir, q, kq) owns gate columns
// 4q..4q+3 and k-slice kq of the dot products. Weight slices live in VGPRs
// (192 per thread for horiz -- invariant of this family). All LDS reads are
// wave-uniform broadcasts (kq == wave index) or stride-1 -> conflict-free.
// Partial z sums combine through a small LDS pbuf during the gate phase.
//
// vert: ~110 VGPR -> __launch_bounds__(512,4) = 2 blocks/CU (overlap gate
// bubbles); x for step s+1 prefetched between barriers A and B.
// horiz: ~235 VGPR -> 1 block/CU; no prefetch (spill risk beats latency win).
// d_out doubles as the v buffer; horiz runs in-place (row staged to LDS
// before any write; each block owns its row exclusively). No workspace use.

#define BB   16
#define SS   256
#define JJ   128   // vertical seq len
#define II   128   // horizontal seq len
#define HID  64
#define G4   256   // 4*HID
#define DV   12    // vertical input dim
#define DH   128   // horizontal input dim

typedef float f32x2 __attribute__((ext_vector_type(2)));
#define PKFMA(a, b, c) __builtin_elementwise_fma((a), (b), (c))

__device__ __forceinline__ float sigf(float x) {
    return 1.0f / (1.0f + __expf(-x));
}
__device__ __forceinline__ float tanhfast(float x) {
    return 1.0f - 2.0f / (1.0f + __expf(2.0f * x));  // saturates correctly
}

// ---------------- vertical sweep: both dirs in one block -------------------
// 2048 blocks (one per b,icol), 512 threads: tid>>8 = dir, t=tid&255,
// q=t&63 (cols 4q..4q+3), kq=t>>6 (k-slice == wave index within dir).
__global__ __launch_bounds__(512, 4)
void vert_kernel(const float* __restrict__ inp,
                 const float* __restrict__ Wud, const float* __restrict__ Uud,
                 const float* __restrict__ bud,
                 const float* __restrict__ Wdu, const float* __restrict__ Udu,
                 const float* __restrict__ bdu,
                 float* __restrict__ v /* [B][J][I][128] */)
{
    const int tid = threadIdx.x;
    const int dir = tid >> 8;          // 0 = ud, 1 = du
    const int t   = tid & 255;
    const int q   = t & 63;            // column quad
    const int kq  = t >> 6;            // k slice (== wave index within dir)
    const int b    = blockIdx.x >> 7;
    const int icol = blockIdx.x & 127;

    const float* W    = dir ? Wdu : Wud;
    const float* U    = dir ? Udu : Uud;
    const float* bias = dir ? bdu : bud;

    __shared__ float xs[JJ][16];        // padded 12->16; 8 KB
    __shared__ float pbuf[2][4][G4];    // partial z sums; 8 KB
    __shared__ float hl[2][HID];

    // stage x: (jt, d=p*6+qq*3+c) <- inp[((b*SS+jt*2+p)*SS + icol*2+qq)*3 + c]
    for (int idx = tid; idx < JJ * DV; idx += 512) {
        int jt  = idx / DV;
        int d   = idx % DV;
        int p   = d / 6;
        int rem = d % 6;
        int row = jt * 2 + p;
        int col = icol * 2 + rem / 3;
        int ch  = rem % 3;
        xs[jt][d] = inp[((b * SS + row) * SS + col) * 3 + ch];
    }
    if (t < HID) hl[dir][t] = 0.0f;

    // weight slices: x-part k in [3kq,3kq+3), U-part k in [16kq,16kq+16)
    f32x2 Wx[3][2];
#pragma unroll
    for (int kk = 0; kk < 3; ++kk)
#pragma unroll
        for (int p = 0; p < 2; ++p)
            Wx[kk][p] = *(const f32x2*)&W[(3 * kq + kk) * G4 + 4 * q + 2 * p];
    f32x2 Up[16][2];
#pragma unroll
    for (int kk = 0; kk < 16; ++kk)
#pragma unroll
        for (int p = 0; p < 2; ++p)
            Up[kk][p] = *(const f32x2*)&U[(16 * kq + kk) * G4 + 4 * q + 2 * p];
    float bg[4] = {0.f, 0.f, 0.f, 0.f};
    if (t < HID) {
#pragma unroll
        for (int g = 0; g < 4; ++g) bg[g] = bias[g * HID + t];
    }

    float ccell = 0.0f;
    const size_t obase = (size_t)b * JJ * II * DH + (size_t)icol * DH + dir * HID + t;
    __syncthreads();   // staging complete

    // prefetch x for step 0
    int t_in = dir ? (JJ - 1) : 0;
    f32x2 px0 = {xs[t_in][3 * kq + 0], xs[t_in][3 * kq + 0]};
    f32x2 px1 = {xs[t_in][3 * kq + 1], xs[t_in][3 * kq + 1]};
    f32x2 px2 = {xs[t_in][3 * kq + 2], xs[t_in][3 * kq + 2]};

    for (int s = 0; s < JJ; ++s) {
        f32x2 a0a = {0.f, 0.f}, a0b = {0.f, 0.f};  // cols 4q,4q+1
        f32x2 a1a = {0.f, 0.f}, a1b = {0.f, 0.f};  // cols 4q+2,4q+3
        // x part from prefetched registers
        a0a = PKFMA(px0, Wx[0][0], a0a); a1a = PKFMA(px0, Wx[0][1], a1a);
        a0b = PKFMA(px1, Wx[1][0], a0b); a1b = PKFMA(px1, Wx[1][1], a1b);
        a0a = PKFMA(px2, Wx[2][0], a0a); a1a = PKFMA(px2, Wx[2][1], a1a);
        // U part: 16 k via 4 broadcast float4 reads
        const float4* hp = (const float4*)&hl[dir][16 * kq];
#pragma unroll
        for (int c4 = 0; c4 < 4; ++c4) {
            float4 h4 = hp[c4];
            f32x2 s0 = {h4.x, h4.x}, s1 = {h4.y, h4.y};
            f32x2 s2 = {h4.z, h4.z}, s3 = {h4.w, h4.w};
            a0a = PKFMA(s0, Up[4 * c4 + 0][0], a0a); a1a = PKFMA(s0, Up[4 * c4 + 0][1], a1a);
            a0b = PKFMA(s1, Up[4 * c4 + 1][0], a0b); a1b = PKFMA(s1, Up[4 * c4 + 1][1], a1b);
            a0a = PKFMA(s2, Up[4 * c4 + 2][0], a0a); a1a = PKFMA(s2, Up[4 * c4 + 2][1], a1a);
            a0b = PKFMA(s3, Up[4 * c4 + 3][0], a0b); a1b = PKFMA(s3, Up[4 * c4 + 3][1], a1b);
        }
        f32x2 r0 = a0a + a0b;
        f32x2 r1 = a1a + a1b;
        *(float4*)&pbuf[dir][kq][4 * q] = make_float4(r0.x, r0.y, r1.x, r1.y);
        __syncthreads();   // A: partials ready for gate reads
        // prefetch x for step s+1 (overlaps gate phase; xs is loop-invariant)
        if (s + 1 < JJ) {
            t_in = dir ? (JJ - 2 - s) : (s + 1);
            float x0 = xs[t_in][3 * kq + 0];
            float x1 = xs[t_in][3 * kq + 1];
            float x2 = xs[t_in][3 * kq + 2];
            px0 = (f32x2){x0, x0};
            px1 = (f32x2){x1, x1};
            px2 = (f32x2){x2, x2};
        }
        if (t < HID) {
            float z0 = bg[0] + pbuf[dir][0][0 * HID + t] + pbuf[dir][1][0 * HID + t]
                             + pbuf[dir][2][0 * HID + t] + pbuf[dir][3][0 * HID + t];
            float z1 = bg[1] + pbuf[dir][0][1 * HID + t] + pbuf[dir][1][1 * HID + t]
                             + pbuf[dir][2][1 * HID + t] + pbuf[dir][3][1 * HID + t];
            float z2 = bg[2] + pbuf[dir][0][2 * HID + t] + pbuf[dir][1][2 * HID + t]
                             + pbuf[dir][2][2 * HID + t] + pbuf[dir][3][2 * HID + t];
            float z3 = bg[3] + pbuf[dir][0][3 * HID + t] + pbuf[dir][1][3 * HID + t]
                             + pbuf[dir][2][3 * HID + t] + pbuf[dir][3][3 * HID + t];
            float ig = sigf(z0), fg = sigf(z1);
            float gg = tanhfast(z2), og = sigf(z3);
            ccell = fg * ccell + ig * gg;
            float hn = og * tanhfast(ccell);
            hl[dir][t] = hn;
            v[obase + (size_t)s * II * DH] = hn;   // output pos == step s
        }
        __syncthreads();   // B: h ready for next step
    }
}

// ---------------- horizontal sweep: both dirs in one block -----------------
// 2048 blocks (one per row b*J+j), 512 threads, same (q,kq) decomposition.
// In-place on d_out: full row staged to LDS before any write.
__global__ __launch_bounds__(512, 2)
void horiz_kernel(const float* __restrict__ Wlr, const float* __restrict__ Ulr,
                  const float* __restrict__ blr,
                  const float* __restrict__ Wrl, const float* __restrict__ Url,
                  const float* __restrict__ brl,
                  float* __restrict__ out /* [B][J][I][128], holds v on entry */)
{
    const int tid = threadIdx.x;
    const int dir = tid >> 8;          // 0 = lr, 1 = rl
    const int t   = tid & 255;
    const int q   = t & 63;
    const int kq  = t >> 6;
    float* rowp = out + (size_t)blockIdx.x * II * DH;

    const float* W    = dir ? Wrl : Wlr;
    const float* U    = dir ? Url : Ulr;
    const float* bias = dir ? brl : blr;

    __shared__ float ys[II][DH];        // 64 KB: full row
    __shared__ float pbuf[2][4][G4];    // 8 KB
    __shared__ float hl[2][HID];

    for (int idx = tid; idx < II * DH / 4; idx += 512)
        ((float4*)ys)[idx] = ((const float4*)rowp)[idx];
    if (t < HID) hl[dir][t] = 0.0f;

    // weight slices: x-part k in [32kq,32kq+32), U-part k in [16kq,16kq+16)
    f32x2 Wx[32][2];
#pragma unroll
    for (int kk = 0; kk < 32; ++kk)
#pragma unroll
        for (int p = 0; p < 2; ++p)
            Wx[kk][p] = *(const f32x2*)&W[(32 * kq + kk) * G4 + 4 * q + 2 * p];
    f32x2 Up[16][2];
#pragma unroll
    for (int kk = 0; kk < 16; ++kk)
#pragma unroll
        for (int p = 0; p < 2; ++p)
            Up[kk][p] = *(const f32x2*)&U[(16 * kq + kk) * G4 + 4 * q + 2 * p];
    float bg[4] = {0.f, 0.f, 0.f, 0.f};
    if (t < HID) {
#pragma unroll
        for (int g = 0; g < 4; ++g) bg[g] = bias[g * HID + t];
    }

    float ccell = 0.0f;
    __syncthreads();   // staging done; safe to overwrite row

    for (int s = 0; s < II; ++s) {
        const int t_in = dir ? (II - 1 - s) : s;
        f32x2 a0a = {0.f, 0.f}, a0b = {0.f, 0.f};
        f32x2 a1a = {0.f, 0.f}, a1b = {0.f, 0.f};
        // x part: 32 k via 8 broadcast float4 reads
        const float4* xp = (const float4*)&ys[t_in][32 * kq];
#pragma unroll
        for (int c4 = 0; c4 < 8; ++c4) {
            float4 x4 = xp[c4];
            f32x2 s0 = {x4.x, x4.x}, s1 = {x4.y, x4.y};
            f32x2 s2 = {x4.z, x4.z}, s3 = {x4.w, x4.w};
            a0a = PKFMA(s0, Wx[4 * c4 + 0][0], a0a); a1a = PKFMA(s0, Wx[4 * c4 + 0][1], a1a);
            a0b = PKFMA(s1, Wx[4 * c4 + 1][0], a0b); a1b = PKFMA(s1, Wx[4 * c4 + 1][1], a1b);
            a0a = PKFMA(s2, Wx[4 * c4 + 2][0], a0a); a1a = PKFMA(s2, Wx[4 * c4 + 2][1], a1a);
            a0b = PKFMA(s3, Wx[4 * c4 + 3][0], a0b); a1b = PKFMA(s3, Wx[4 * c4 + 3][1], a1b);
        }
        // U part: 16 k via 4 broadcast float4 reads
        const float4* hp = (const float4*)&hl[dir][16 * kq];
#pragma unroll
        for (int c4 = 0; c4 < 4; ++c4) {
            float4 h4 = hp[c4];
            f32x2 s0 = {h4.x, h4.x}, s1 = {h4.y, h4.y};
            f32x2 s2 = {h4.z, h4.z}, s3 = {h4.w, h4.w};
            a0a = PKFMA(s0, Up[4 * c4 + 0][0], a0a); a1a = PKFMA(s0, Up[4 * c4 + 0][1], a1a);
            a0b = PKFMA(s1, Up[4 * c4 + 1][0], a0b); a1b = PKFMA(s1, Up[4 * c4 + 1][1], a1b);
            a0a = PKFMA(s2, Up[4 * c4 + 2][0], a0a); a1a = PKFMA(s2, Up[4 * c4 + 2][1], a1a);
            a0b = PKFMA(s3, Up[4 * c4 + 3][0], a0b); a1b = PKFMA(s3, Up[4 * c4 + 3][1], a1b);
        }
        f32x2 r0 = a0a + a0b;
        f32x2 r1 = a1a + a1b;
        *(float4*)&pbuf[dir][kq][4 * q] = make_float4(r0.x, r0.y, r1.x, r1.y);
        __syncthreads();   // A
        if (t < HID) {
            float z0 = bg[0] + pbuf[dir][0][0 * HID + t] + pbuf[dir][1][0 * HID + t]
                             + pbuf[dir][2][0 * HID + t] + pbuf[dir][3][0 * HID + t];
            float z1 = bg[1] + pbuf[dir][0][1 * HID + t] + pbuf[dir][1][1 * HID + t]
                             + pbuf[dir][2][1 * HID + t] + pbuf[dir][3][1 * HID + t];
            float z2 = bg[2] + pbuf[dir][0][2 * HID + t] + pbuf[dir][1][2 * HID + t]
                             + pbuf[dir][2][2 * HID + t] + pbuf[dir][3][2 * HID + t];
            float z3 = bg[3] + pbuf[dir][0][3 * HID + t] + pbuf[dir][1][3 * HID + t]
                             + pbuf[dir][2][3 * HID + t] + pbuf[dir][3][3 * HID + t];
            float ig = sigf(z0), fg = sigf(z1);
            float gg = tanhfast(z2), og = sigf(z3);
            ccell = fg * ccell + ig * gg;
            float hn = og * tanhfast(ccell);
            hl[dir][t] = hn;
            rowp[s * DH + dir * HID + t] = hn;
        }
        __syncthreads();   // B
    }
}

extern "C" void kernel_launch(void* const* d_in, const int* in_sizes, int n_in,
                              void* d_out, int out_size, void* d_ws, size_t ws_size,
                              hipStream_t stream)
{
    const float* inp = (const float*)d_in[0];
    const float* Wud = (const float*)d_in[1];
    const float* Uud = (const float*)d_in[2];
    const float* bud = (const float*)d_in[3];
    const float* Wdu = (const float*)d_in[4];
    const float* Udu = (const float*)d_in[5];
    const float* bdu = (const float*)d_in[6];
    const float* Wlr = (const float*)d_in[7];
    const float* Ulr = (const float*)d_in[8];
    const float* blr = (const float*)d_in[9];
    const float* Wrl = (const float*)d_in[10];
    const float* Url = (const float*)d_in[11];
    const float* brl = (const float*)d_in[12];
    float* out = (float*)d_out;

    vert_kernel<<<BB * II, 512, 0, stream>>>(inp, Wud, Uud, bud,
                                             Wdu, Udu, bdu, out);
    horiz_kernel<<<BB * JJ, 512, 0, stream>>>(Wlr, Ulr, blr,
                                              Wrl, Url, brl, out);
}

// Round 5
// 1105.731 us; speedup vs baseline: 1.5226x; 1.5226x over previous
//
#include <hip/hip_runtime.h>
#include <math.h>

// ReNet: vertical sweep kept as passing fp32 kernel (unchanged from R3).
// Horizontal sweep REWRITTEN as bf16 split-precision MFMA recurrence:
//   - block = 4 sequence rows x both dirs; M=16 = [8 hi rows | 8 lo rows]
//     (Ootomo split: y = hi+lo bf16; C accumulates A*Bhi + A*Blo -> all four
//      hi/lo cross terms land in C rows r and r+8; summed at gate time.
//      Effective precision ~1e-5 rel, far under fp32-test tolerance.)
//   - N=512 gate cols = [lr 256 | rl 256]; K=192 = [y 128 | h 64].
//   - weights as MFMA B-fragments in regs/AGPRs (AGPR is free for MFMA, the
//     R4 counter evidence showed AGPR is fatal only for VALU operands).
//   - in-place d_out: rl needs y positions 0..63 after they're overwritten;
//     a 128 KB LDS fp32 stash preserves them. All other reads precede writes.
// Grid: 512 blocks x 512 thr (8 waves; waves 0-3 lr gates, 4-7 rl gates).

#define BB   16
#define SS   256
#define JJ   128
#define II   128
#define HID  64
#define G4   256
#define DV   12
#define DH   128

typedef float f32x2 __attribute__((ext_vector_type(2)));
typedef float f32x4 __attribute__((ext_vector_type(4)));
typedef short short8 __attribute__((ext_vector_type(8)));
typedef short short4s __attribute__((ext_vector_type(4)));
#define PKFMA(a, b, c) __builtin_elementwise_fma((a), (b), (c))

__device__ __forceinline__ float sigf(float x) { return 1.0f / (1.0f + __expf(-x)); }
__device__ __forceinline__ float tanhfast(float x) { return 1.0f - 2.0f / (1.0f + __expf(2.0f * x)); }

__device__ __forceinline__ unsigned short f2bf(float f) {
    union { float f; unsigned u; } v; v.f = f;
    unsigned r = v.u + 0x7FFFu + ((v.u >> 16) & 1u);   // RNE
    return (unsigned short)(r >> 16);
}
__device__ __forceinline__ float bf2f(unsigned short h) {
    union { unsigned u; float f; } v; v.u = ((unsigned)h) << 16;
    return v.f;
}

// ==================== vertical sweep (unchanged, passing) ==================
__global__ __launch_bounds__(512, 4)
void vert_kernel(const float* __restrict__ inp,
                 const float* __restrict__ Wud, const float* __restrict__ Uud,
                 const float* __restrict__ bud,
                 const float* __restrict__ Wdu, const float* __restrict__ Udu,
                 const float* __restrict__ bdu,
                 float* __restrict__ v)
{
    const int tid = threadIdx.x;
    const int dir = tid >> 8;
    const int t   = tid & 255;
    const int q   = t & 63;
    const int kq  = t >> 6;
    const int b    = blockIdx.x >> 7;
    const int icol = blockIdx.x & 127;

    const float* W    = dir ? Wdu : Wud;
    const float* U    = dir ? Udu : Uud;
    const float* bias = dir ? bdu : bud;

    __shared__ float xs[JJ][16];
    __shared__ float pbuf[2][4][G4];
    __shared__ float hl[2][HID];

    for (int idx = tid; idx < JJ * DV; idx += 512) {
        int jt  = idx / DV;
        int d   = idx % DV;
        int p   = d / 6;
        int rem = d % 6;
        int row = jt * 2 + p;
        int col = icol * 2 + rem / 3;
        int ch  = rem % 3;
        xs[jt][d] = inp[((b * SS + row) * SS + col) * 3 + ch];
    }
    if (t < HID) hl[dir][t] = 0.0f;

    f32x2 Wx[3][2];
#pragma unroll
    for (int kk = 0; kk < 3; ++kk)
#pragma unroll
        for (int p = 0; p < 2; ++p)
            Wx[kk][p] = *(const f32x2*)&W[(3 * kq + kk) * G4 + 4 * q + 2 * p];
    f32x2 Up[16][2];
#pragma unroll
    for (int kk = 0; kk < 16; ++kk)
#pragma unroll
        for (int p = 0; p < 2; ++p)
            Up[kk][p] = *(const f32x2*)&U[(16 * kq + kk) * G4 + 4 * q + 2 * p];
    float bg[4] = {0.f, 0.f, 0.f, 0.f};
    if (t < HID) {
#pragma unroll
        for (int g = 0; g < 4; ++g) bg[g] = bias[g * HID + t];
    }

    float ccell = 0.0f;
    const size_t obase = (size_t)b * JJ * II * DH + (size_t)icol * DH + dir * HID + t;
    __syncthreads();

    int t_in = dir ? (JJ - 1) : 0;
    f32x2 px0 = {xs[t_in][3 * kq + 0], xs[t_in][3 * kq + 0]};
    f32x2 px1 = {xs[t_in][3 * kq + 1], xs[t_in][3 * kq + 1]};
    f32x2 px2 = {xs[t_in][3 * kq + 2], xs[t_in][3 * kq + 2]};

    for (int s = 0; s < JJ; ++s) {
        f32x2 a0a = {0.f, 0.f}, a0b = {0.f, 0.f};
        f32x2 a1a = {0.f, 0.f}, a1b = {0.f, 0.f};
        a0a = PKFMA(px0, Wx[0][0], a0a); a1a = PKFMA(px0, Wx[0][1], a1a);
        a0b = PKFMA(px1, Wx[1][0], a0b); a1b = PKFMA(px1, Wx[1][1], a1b);
        a0a = PKFMA(px2, Wx[2][0], a0a); a1a = PKFMA(px2, Wx[2][1], a1a);
        const float4* hp = (const float4*)&hl[dir][16 * kq];
#pragma unroll
        for (int c4 = 0; c4 < 4; ++c4) {
            float4 h4 = hp[c4];
            f32x2 s0 = {h4.x, h4.x}, s1 = {h4.y, h4.y};
            f32x2 s2 = {h4.z, h4.z}, s3 = {h4.w, h4.w};
            a0a = PKFMA(s0, Up[4 * c4 + 0][0], a0a); a1a = PKFMA(s0, Up[4 * c4 + 0][1], a1a);
            a0b = PKFMA(s1, Up[4 * c4 + 1][0], a0b); a1b = PKFMA(s1, Up[4 * c4 + 1][1], a1b);
            a0a = PKFMA(s2, Up[4 * c4 + 2][0], a0a); a1a = PKFMA(s2, Up[4 * c4 + 2][1], a1a);
            a0b = PKFMA(s3, Up[4 * c4 + 3][0], a0b); a1b = PKFMA(s3, Up[4 * c4 + 3][1], a1b);
        }
        f32x2 r0 = a0a + a0b;
        f32x2 r1 = a1a + a1b;
        *(float4*)&pbuf[dir][kq][4 * q] = make_float4(r0.x, r0.y, r1.x, r1.y);
        __syncthreads();
        if (s + 1 < JJ) {
            t_in = dir ? (JJ - 2 - s) : (s + 1);
            float x0 = xs[t_in][3 * kq + 0];
            float x1 = xs[t_in][3 * kq + 1];
            float x2 = xs[t_in][3 * kq + 2];
            px0 = (f32x2){x0, x0};
            px1 = (f32x2){x1, x1};
            px2 = (f32x2){x2, x2};
        }
        if (t < HID) {
            float z0 = bg[0] + pbuf[dir][0][0 * HID + t] + pbuf[dir][1][0 * HID + t]
                             + pbuf[dir][2][0 * HID + t] + pbuf[dir][3][0 * HID + t];
            float z1 = bg[1] + pbuf[dir][0][1 * HID + t] + pbuf[dir][1][1 * HID + t]
                             + pbuf[dir][2][1 * HID + t] + pbuf[dir][3][1 * HID + t];
            float z2 = bg[2] + pbuf[dir][0][2 * HID + t] + pbuf[dir][1][2 * HID + t]
                             + pbuf[dir][2][2 * HID + t] + pbuf[dir][3][2 * HID + t];
            float z3 = bg[3] + pbuf[dir][0][3 * HID + t] + pbuf[dir][1][3 * HID + t]
                             + pbuf[dir][2][3 * HID + t] + pbuf[dir][3][3 * HID + t];
            float ig = sigf(z0), fg = sigf(z1);
            float gg = tanhfast(z2), og = sigf(z3);
            ccell = fg * ccell + ig * gg;
            float hn = og * tanhfast(ccell);
            hl[dir][t] = hn;
            v[obase + (size_t)s * II * DH] = hn;
        }
        __syncthreads();
    }
}

// ==================== horizontal sweep: bf16-split MFMA ====================
// 512 blocks x 512 threads. Block owns 4 sequence rows (b,j). Per step:
//   A[16 x 192] bf16 in LDS (rows 0-7 hi = [lr p0-3 | rl p0-3], rows 8-15 lo)
//   C[16 x 512] = A*Bhi + A*Blo accumulated in one f32 frag per N-tile.
//   z[dp][hid][gt] = C[dp] + C[dp+8]  (hi*hi + hi*lo + lo*hi + lo*lo).
__global__ __launch_bounds__(512, 2)
void horiz_mfma(const float* __restrict__ Wlr, const float* __restrict__ Ulr,
                const float* __restrict__ blr,
                const float* __restrict__ Wrl, const float* __restrict__ Url,
                const float* __restrict__ brl,
                float* __restrict__ out /* [2048 rows][128 pos][128 ch] */)
{
    __shared__ float stash[64][4][128];          // 128 KB: y positions 0..63
    __shared__ unsigned short abuf[2][16 * 192]; // 12 KB: A double-buffer
    __shared__ float zbuf[8 * 64 * 9];           // 18 KB: stride-9 (bank-free)

    const int tid  = threadIdx.x;
    const int w    = tid >> 6;       // wave 0..7
    const int l    = tid & 63;       // lane
    const int dirw = w >> 2;         // which dir's weights this wave holds
    const int gt4  = w & 3;          // gate type (keras i,f,g,o) of this wave
    const int rowbase = blockIdx.x * 4;

    // ---- B fragments (bf16 hi/lo split), live in regs/AGPRs --------------
    const float* Wp = dirw ? Wrl : Wlr;
    const float* Up = dirw ? Url : Ulr;
    short8 Bh[4][6], Bl[4][6];
#pragma unroll
    for (int nt = 0; nt < 4; ++nt) {
        const int gl = gt4 * 64 + nt * 16 + (l & 15);
#pragma unroll
        for (int kt = 0; kt < 6; ++kt) {
#pragma unroll
            for (int j = 0; j < 8; ++j) {
                int k = kt * 32 + ((l >> 4) << 3) + j;
                float vv = (k < DH) ? Wp[k * G4 + gl] : Up[(k - DH) * G4 + gl];
                unsigned short hh = f2bf(vv);
                Bh[nt][kt][j] = (short)hh;
                Bl[nt][kt][j] = (short)f2bf(vv - bf2f(hh));
            }
        }
    }

    // update-thread identity: one (dir, pair, hid) per thread
    const int udir = tid >> 8;
    const int up   = (tid >> 6) & 3;
    const int uhid = tid & 63;
    const int udp  = udir * 4 + up;
    const float* bp = udir ? brl : blr;
    const float bias_i = bp[0 * HID + uhid], bias_f = bp[1 * HID + uhid];
    const float bias_g = bp[2 * HID + uhid], bias_o = bp[3 * HID + uhid];
    float c_reg = 0.0f;
    const int orow = rowbase + up;

    // loader identity (threads 0..255): (dir, pair, 4-channel chunk)
    const bool isload = (tid < 256);
    const int ldir = (tid >> 7) & 1;
    const int lp   = (tid >> 5) & 3;
    const int lc4  = (tid & 31) * 4;

    // ---- prologue: zero h-region of abuf[0]; stage step-0 y; fill stash[0]
    for (int i = tid; i < 16 * 64; i += 512) {
        int row = i >> 6, kk = 128 + (i & 63);
        abuf[0][(row * 192 + kk) ^ ((row & 7) << 3)] = 0;
    }
    if (isload) {
        int pos = ldir ? 127 : 0;
        float4 yv = *(const float4*)&out[((size_t)(rowbase + lp) * II + pos) * DH + lc4];
        int rowh = ldir * 4 + lp;
        short4s hv, lv;
#pragma unroll
        for (int j = 0; j < 4; ++j) {
            float x = ((const float*)&yv)[j];
            unsigned short hh = f2bf(x);
            hv[j] = (short)hh;
            lv[j] = (short)f2bf(x - bf2f(hh));
        }
        *(short4s*)&abuf[0][(rowh * 192 + lc4) ^ ((rowh & 7) << 3)] = hv;
        *(short4s*)&abuf[0][((rowh + 8) * 192 + lc4) ^ ((rowh & 7) << 3)] = lv;
        if (ldir == 0) *(float4*)&stash[0][lp][lc4] = yv;
    }
    __syncthreads();

    for (int s = 0; s < II; ++s) {
        const int buf = s & 1;

        // -- prefetch next step's y (regs); rl late steps come from stash --
        float4 yv;
        bool have_y = false;
        if (isload && s < II - 1) {
            int pos = ldir ? (126 - s) : (s + 1);
            if (ldir && pos < 64)
                yv = *(const float4*)&stash[pos][lp][lc4];
            else
                yv = *(const float4*)&out[((size_t)(rowbase + lp) * II + pos) * DH + lc4];
            have_y = true;
        }

        // -- A fragments: row = l&15, k-chunk = (l>>4)*8 + 32*kt ----------
        short8 A[6];
#pragma unroll
        for (int kt = 0; kt < 6; ++kt) {
            int row = l & 15;
            int idx = (row * 192 + kt * 32 + ((l >> 4) << 3)) ^ ((row & 7) << 3);
            A[kt] = *(const short8*)&abuf[buf][idx];
        }

        // -- MFMA: C = A*Bhi + A*Blo per N-tile; write valid rows to zbuf --
        const int lg = l >> 4;
#pragma unroll
        for (int nt = 0; nt < 4; ++nt) {
            f32x4 C = {0.f, 0.f, 0.f, 0.f};
#pragma unroll
            for (int kt = 0; kt < 6; ++kt)
                C = __builtin_amdgcn_mfma_f32_16x16x32_bf16(A[kt], Bh[nt][kt], C, 0, 0, 0);
#pragma unroll
            for (int kt = 0; kt < 6; ++kt)
                C = __builtin_amdgcn_mfma_f32_16x16x32_bf16(A[kt], Bl[nt][kt], C, 0, 0, 0);
            if ((lg & 1) == dirw) {                  // rows of this wave's dir
                int hid = nt * 16 + (l & 15);
                int part = lg >> 1;                  // 0 = hi-rows, 1 = lo-rows
#pragma unroll
                for (int r = 0; r < 4; ++r) {
                    int dp = dirw * 4 + r;
                    zbuf[(dp * 64 + hid) * 9 + part * 4 + gt4] = C[r];
                }
            }
        }
        __syncthreads();   // barrier 1: zbuf complete

        // -- gate + cell update (all 512 threads, one (dir,p,hid) each) ----
        {
            int base = (udp * 64 + uhid) * 9;
            float zi = zbuf[base + 0] + zbuf[base + 4] + bias_i;
            float zf = zbuf[base + 1] + zbuf[base + 5] + bias_f;
            float zg = zbuf[base + 2] + zbuf[base + 6] + bias_g;
            float zo = zbuf[base + 3] + zbuf[base + 7] + bias_o;
            float ig = sigf(zi), fg = sigf(zf);
            float gg = tanhfast(zg), og = sigf(zo);
            c_reg = fg * c_reg + ig * gg;
            float hn = og * tanhfast(c_reg);
            out[((size_t)orow * II + s) * DH + udir * 64 + uhid] = hn;
            unsigned short hh = f2bf(hn);
            unsigned short hlo = f2bf(hn - bf2f(hh));
            int nb = buf ^ 1;
            abuf[nb][(udp * 192 + 128 + uhid) ^ ((udp & 7) << 3)] = (short)hh;
            abuf[nb][((udp + 8) * 192 + 128 + uhid) ^ ((udp & 7) << 3)] = (short)hlo;
        }

        // -- write staged y into next A buffer; maintain stash -------------
        if (have_y) {
            int nb = buf ^ 1;
            int rowh = ldir * 4 + lp;
            short4s hv, lv;
#pragma unroll
            for (int j = 0; j < 4; ++j) {
                float x = ((const float*)&yv)[j];
                unsigned short hh = f2bf(x);
                hv[j] = (short)hh;
                lv[j] = (short)f2bf(x - bf2f(hh));
            }
            *(short4s*)&abuf[nb][(rowh * 192 + lc4) ^ ((rowh & 7) << 3)] = hv;
            *(short4s*)&abuf[nb][((rowh + 8) * 192 + lc4) ^ ((rowh & 7) << 3)] = lv;
            if (ldir == 0 && (s + 1) < 64) *(float4*)&stash[s + 1][lp][lc4] = yv;
        }
        __syncthreads();   // barrier 2: next A buffer ready
    }
}

extern "C" void kernel_launch(void* const* d_in, const int* in_sizes, int n_in,
                              void* d_out, int out_size, void* d_ws, size_t ws_size,
                              hipStream_t stream)
{
    const float* inp = (const float*)d_in[0];
    const float* Wud = (const float*)d_in[1];
    const float* Uud = (const float*)d_in[2];
    const float* bud = (const float*)d_in[3];
    const float* Wdu = (const float*)d_in[4];
    const float* Udu = (const float*)d_in[5];
    const float* bdu = (const float*)d_in[6];
    const float* Wlr = (const float*)d_in[7];
    const float* Ulr = (const float*)d_in[8];
    const float* blr = (const float*)d_in[9];
    const float* Wrl = (const float*)d_in[10];
    const float* Url = (const float*)d_in[11];
    const float* brl = (const float*)d_in[12];
    float* out = (float*)d_out;

    vert_kernel<<<BB * II, 512, 0, stream>>>(inp, Wud, Uud, bud,
                                             Wdu, Udu, bdu, out);
    horiz_mfma<<<(BB * JJ) / 4, 512, 0, stream>>>(Wlr, Ulr, blr,
                                                  Wrl, Url, brl, out);
}

// Round 6
// 785.560 us; speedup vs baseline: 2.1432x; 1.4076x over previous
//
#include <hip/hip_runtime.h>
#include <math.h>

// ReNet: 4 LSTMs. Both sweeps now bf16 split-precision MFMA recurrences
// (Ootomo hi/lo split in the M dimension; fp32 accumulate), batched 8
// sequences per block so grid = 256 = exactly 1 block/CU, single round.
// Measured insight (R5): per block-step serial cost ~2.1us regardless of
// path -> amortize it over more recurrences per block.
// v intermediate goes to d_ws when large enough (no in-place hazard);
// otherwise falls back to the R5 in-place horiz kernel (stash path).

#define BB   16
#define SS   256
#define JJ   128
#define II   128
#define HID  64
#define G4   256
#define DV   12
#define DH   128

typedef float f32x4 __attribute__((ext_vector_type(4)));
typedef short short8 __attribute__((ext_vector_type(8)));
typedef short short4s __attribute__((ext_vector_type(4)));

__device__ __forceinline__ float sigf(float x) { return 1.0f / (1.0f + __expf(-x)); }
__device__ __forceinline__ float tanhfast(float x) { return 1.0f - 2.0f / (1.0f + __expf(2.0f * x)); }

__device__ __forceinline__ unsigned short f2bf(float f) {
    union { float f; unsigned u; } v; v.f = f;
    unsigned r = v.u + 0x7FFFu + ((v.u >> 16) & 1u);   // RNE
    return (unsigned short)(r >> 16);
}
__device__ __forceinline__ float bf2f(unsigned short h) {
    union { unsigned u; float f; } v; v.u = ((unsigned)h) << 16;
    return v.f;
}

// ==================== vertical sweep: SEQ=8 MFMA, grid 256 =================
// Block owns 8 (b,icol) sequences, both dirs. A-tile per dir: 16 rows =
// [seq0-7 hi | seq0-7 lo], K=96 (x 0..11, h 12..75, pad). 8 waves:
// dirw = w>>2 (which dir), gt4 = w&3 (gate type), 4 N-tiles each.
__global__ __launch_bounds__(512, 2)
void vert_mfma(const float* __restrict__ inp,
               const float* __restrict__ Wud, const float* __restrict__ Uud,
               const float* __restrict__ bud,
               const float* __restrict__ Wdu, const float* __restrict__ Udu,
               const float* __restrict__ bdu,
               float* __restrict__ vdst)
{
    __shared__ unsigned short xh[8][JJ][DV];      // 24 KB
    __shared__ unsigned short xl[8][JJ][DV];      // 24 KB
    __shared__ unsigned short abuf[2][2][16 * 128]; // 16 KB  [buf][dir-tile]
    __shared__ float zbuf[16 * 64 * 9];           // 36 KB

    const int tid  = threadIdx.x;
    const int w    = tid >> 6, l = tid & 63;
    const int dirw = w >> 2, gt4 = w & 3, lg = l >> 4;
    const int seq0 = blockIdx.x * 8;
    const int b     = seq0 >> 7;
    const int icol0 = seq0 & 127;

    // ---- stage x as bf16 hi/lo (coalesced 48-float runs per image row) ----
    for (int idx = tid; idx < 256 * 48; idx += 512) {
        int row = idx / 48;            // image row = 2t+p
        int wi  = idx % 48;
        int seq = wi / 6, qc = wi % 6;
        int t = row >> 1;
        int k = (row & 1) * 6 + qc;    // p*6 + q*3 + c
        float x = inp[(size_t)(b * SS + row) * 768 + (icol0 + seq) * 6 + qc];
        unsigned short hh = f2bf(x);
        xh[seq][t][k] = hh;
        xl[seq][t][k] = f2bf(x - bf2f(hh));
    }
    // zero both A buffers (establishes h=0 and the k=76..127 pad = 0)
    for (int i = tid; i < 2 * 2 * 16 * 128; i += 512)
        ((unsigned short*)abuf)[i] = 0;

    // ---- B fragments (dir dirw, gate gt4, 4 N-tiles, K=96 = 3 k-tiles) ----
    const float* Wp = dirw ? Wdu : Wud;
    const float* Ut = dirw ? Udu : Uud;
    short8 Bh[4][3], Bl[4][3];
#pragma unroll
    for (int nt = 0; nt < 4; ++nt) {
        const int gl = gt4 * 64 + nt * 16 + (l & 15);
#pragma unroll
        for (int kt = 0; kt < 3; ++kt) {
#pragma unroll
            for (int j = 0; j < 8; ++j) {
                int k = kt * 32 + lg * 8 + j;
                float vv = (k < DV) ? Wp[k * G4 + gl]
                         : (k < DV + HID ? Ut[(k - DV) * G4 + gl] : 0.0f);
                unsigned short hh = f2bf(vv);
                Bh[nt][kt][j] = (short)hh;
                Bl[nt][kt][j] = (short)f2bf(vv - bf2f(hh));
            }
        }
    }

    const int uhid = tid & 63, usq = tid >> 6;     // gate-update identity
    float bA[4], bD[4];
#pragma unroll
    for (int g = 0; g < 4; ++g) { bA[g] = bud[g * HID + uhid]; bD[g] = bdu[g * HID + uhid]; }
    float c0 = 0.0f, c1 = 0.0f;
    __syncthreads();

    // step-0 x into buf 0 (dir0 t=0, dir1 t=127)
    if (tid < 192) {
        int d = tid / 96, r = (tid % 96) / 12, k = tid % 12;
        int t = d ? 127 : 0;
        int idx = (((k >> 3) ^ r) << 3) + (k & 7);
        abuf[0][d][r * 128 + idx]       = xh[r][t][k];
        abuf[0][d][(r + 8) * 128 + idx] = xl[r][t][k];
    }
    __syncthreads();

    for (int s = 0; s < JJ; ++s) {
        const int buf = s & 1, nb = buf ^ 1;

        short8 A[3];
#pragma unroll
        for (int kt = 0; kt < 3; ++kt)
            A[kt] = *(const short8*)&abuf[buf][dirw]
                     [(l & 15) * 128 + ((((kt << 2) | lg) ^ (l & 7)) << 3)];

#pragma unroll
        for (int nt = 0; nt < 4; ++nt) {
            f32x4 C = {0.f, 0.f, 0.f, 0.f};
#pragma unroll
            for (int kt = 0; kt < 3; ++kt)
                C = __builtin_amdgcn_mfma_f32_16x16x32_bf16(A[kt], Bh[nt][kt], C, 0, 0, 0);
#pragma unroll
            for (int kt = 0; kt < 3; ++kt)
                C = __builtin_amdgcn_mfma_f32_16x16x32_bf16(A[kt], Bl[nt][kt], C, 0, 0, 0);
            const int part = lg >> 1, sb = (lg & 1) * 4;
            const int hid = nt * 16 + (l & 15);
#pragma unroll
            for (int r = 0; r < 4; ++r)
                zbuf[((dirw * 8 + sb + r) * 64 + hid) * 9 + part * 4 + gt4] = C[r];
        }
        __syncthreads();   // barrier 1: zbuf complete

        {   // u=0: dir0 (ud), dp = usq
            int base = (usq * 64 + uhid) * 9;
            float zi = zbuf[base + 0] + zbuf[base + 4] + bA[0];
            float zf = zbuf[base + 1] + zbuf[base + 5] + bA[1];
            float zg = zbuf[base + 2] + zbuf[base + 6] + bA[2];
            float zo = zbuf[base + 3] + zbuf[base + 7] + bA[3];
            float ig = sigf(zi), fg = sigf(zf), gg = tanhfast(zg), og = sigf(zo);
            c0 = fg * c0 + ig * gg;
            float hn = og * tanhfast(c0);
            vdst[((size_t)(b * JJ + s) * II + icol0 + usq) * DH + uhid] = hn;
            unsigned short hh = f2bf(hn);
            int k12 = 12 + uhid;
            int idx = (((k12 >> 3) ^ usq) << 3) + (k12 & 7);
            abuf[nb][0][usq * 128 + idx]       = hh;
            abuf[nb][0][(usq + 8) * 128 + idx] = f2bf(hn - bf2f(hh));
        }
        {   // u=1: dir1 (du), dp = 8+usq
            int base = ((8 + usq) * 64 + uhid) * 9;
            float zi = zbuf[base + 0] + zbuf[base + 4] + bD[0];
            float zf = zbuf[base + 1] + zbuf[base + 5] + bD[1];
            float zg = zbuf[base + 2] + zbuf[base + 6] + bD[2];
            float zo = zbuf[base + 3] + zbuf[base + 7] + bD[3];
            float ig = sigf(zi), fg = sigf(zf), gg = tanhfast(zg), og = sigf(zo);
            c1 = fg * c1 + ig * gg;
            float hn = og * tanhfast(c1);
            vdst[((size_t)(b * JJ + s) * II + icol0 + usq) * DH + 64 + uhid] = hn;
            unsigned short hh = f2bf(hn);
            int k12 = 12 + uhid;
            int idx = (((k12 >> 3) ^ usq) << 3) + (k12 & 7);
            abuf[nb][1][usq * 128 + idx]       = hh;
            abuf[nb][1][(usq + 8) * 128 + idx] = f2bf(hn - bf2f(hh));
        }
        // next step's x
        if (s + 1 < JJ && tid < 192) {
            int d = tid / 96, r = (tid % 96) / 12, k = tid % 12;
            int t = d ? (126 - s) : (s + 1);
            int idx = (((k >> 3) ^ r) << 3) + (k & 7);
            abuf[nb][d][r * 128 + idx]       = xh[r][t][k];
            abuf[nb][d][(r + 8) * 128 + idx] = xl[r][t][k];
        }
        __syncthreads();   // barrier 2: next A buffer ready
    }
}

// ============ horizontal sweep: SEQ=8 MFMA, v from workspace ===============
// Block owns 8 output rows; reads v from vsrc (d_ws), writes out. No stash.
// A-tile per dir: 16 rows = [seq0-7 hi | lo], K=192 (y 0..127, h 128..191).
__global__ __launch_bounds__(512, 2)
void horiz_mfma8(const float* __restrict__ Wlr, const float* __restrict__ Ulr,
                 const float* __restrict__ blr,
                 const float* __restrict__ Wrl, const float* __restrict__ Url,
                 const float* __restrict__ brl,
                 const float* __restrict__ vsrc,
                 float* __restrict__ out)
{
    __shared__ unsigned short abuf[2][2][16 * 192]; // 24 KB
    __shared__ float zbuf[16 * 64 * 9];             // 36 KB

    const int tid  = threadIdx.x;
    const int w    = tid >> 6, l = tid & 63;
    const int dirw = w >> 2, gt4 = w & 3, lg = l >> 4;
    const int rowbase = blockIdx.x * 8;

    // B fragments: 4 N-tiles x 6 k-tiles, hi/lo
    const float* Wp = dirw ? Wrl : Wlr;
    const float* Ut = dirw ? Url : Ulr;
    short8 Bh[4][6], Bl[4][6];
#pragma unroll
    for (int nt = 0; nt < 4; ++nt) {
        const int gl = gt4 * 64 + nt * 16 + (l & 15);
#pragma unroll
        for (int kt = 0; kt < 6; ++kt) {
#pragma unroll
            for (int j = 0; j < 8; ++j) {
                int k = kt * 32 + lg * 8 + j;
                float vv = (k < DH) ? Wp[k * G4 + gl] : Ut[(k - DH) * G4 + gl];
                unsigned short hh = f2bf(vv);
                Bh[nt][kt][j] = (short)hh;
                Bl[nt][kt][j] = (short)f2bf(vv - bf2f(hh));
            }
        }
    }

    const int uhid = tid & 63, usq = tid >> 6;
    float bA[4], bD[4];
#pragma unroll
    for (int g = 0; g < 4; ++g) { bA[g] = blr[g * HID + uhid]; bD[g] = brl[g * HID + uhid]; }
    float c0 = 0.0f, c1 = 0.0f;

    // y-loader identity: (d, seq, 4-ch chunk)
    const int yd = tid >> 8, ysq = (tid >> 5) & 7, yc4 = (tid & 31) << 2;

    // prologue: zero h region of buf0; stage step-0 y
    for (int i = tid; i < 2 * 16 * 64; i += 512) {
        int tile = i >> 10, rr = (i >> 6) & 15, kk = 128 + (i & 63);
        abuf[0][tile][rr * 192 + ((((kk >> 3)) ^ (rr & 7)) << 3) + (kk & 7)] = 0;
    }
    {
        int pos = yd ? 127 : 0;
        float4 yv = *(const float4*)&vsrc[((size_t)(rowbase + ysq) * II + pos) * DH + yc4];
        int idx = (((yc4 >> 3) ^ ysq) << 3) + (yc4 & 7);
        short4s hv, lv;
#pragma unroll
        for (int j = 0; j < 4; ++j) {
            float x = ((const float*)&yv)[j];
            unsigned short hh = f2bf(x);
            hv[j] = (short)hh; lv[j] = (short)f2bf(x - bf2f(hh));
        }
        *(short4s*)&abuf[0][yd][ysq * 192 + idx]       = hv;
        *(short4s*)&abuf[0][yd][(ysq + 8) * 192 + idx] = lv;
    }
    __syncthreads();

    for (int s = 0; s < II; ++s) {
        const int buf = s & 1, nb = buf ^ 1;

        // prefetch next y (global, overlaps MFMA)
        float4 yv;
        const bool have_y = (s < II - 1);
        if (have_y) {
            int pos = yd ? (126 - s) : (s + 1);
            yv = *(const float4*)&vsrc[((size_t)(rowbase + ysq) * II + pos) * DH + yc4];
        }

        short8 A[6];
#pragma unroll
        for (int kt = 0; kt < 6; ++kt)
            A[kt] = *(const short8*)&abuf[buf][dirw]
                     [(l & 15) * 192 + ((((kt << 2) | lg) ^ (l & 7)) << 3)];

#pragma unroll
        for (int nt = 0; nt < 4; ++nt) {
            f32x4 C = {0.f, 0.f, 0.f, 0.f};
#pragma unroll
            for (int kt = 0; kt < 6; ++kt)
                C = __builtin_amdgcn_mfma_f32_16x16x32_bf16(A[kt], Bh[nt][kt], C, 0, 0, 0);
#pragma unroll
            for (int kt = 0; kt < 6; ++kt)
                C = __builtin_amdgcn_mfma_f32_16x16x32_bf16(A[kt], Bl[nt][kt], C, 0, 0, 0);
            const int part = lg >> 1, sb = (lg & 1) * 4;
            const int hid = nt * 16 + (l & 15);
#pragma unroll
            for (int r = 0; r < 4; ++r)
                zbuf[((dirw * 8 + sb + r) * 64 + hid) * 9 + part * 4 + gt4] = C[r];
        }
        __syncthreads();   // barrier 1

        {   // u=0: lr
            int base = (usq * 64 + uhid) * 9;
            float zi = zbuf[base + 0] + zbuf[base + 4] + bA[0];
            float zf = zbuf[base + 1] + zbuf[base + 5] + bA[1];
            float zg = zbuf[base + 2] + zbuf[base + 6] + bA[2];
            float zo = zbuf[base + 3] + zbuf[base + 7] + bA[3];
            float ig = sigf(zi), fg = sigf(zf), gg = tanhfast(zg), og = sigf(zo);
            c0 = fg * c0 + ig * gg;
            float hn = og * tanhfast(c0);
            out[((size_t)(rowbase + usq) * II + s) * DH + uhid] = hn;
            unsigned short hh = f2bf(hn);
            int kk = 128 + uhid;
            int idx = (((kk >> 3) ^ usq) << 3) + (kk & 7);
            abuf[nb][0][usq * 192 + idx]       = hh;
            abuf[nb][0][(usq + 8) * 192 + idx] = f2bf(hn - bf2f(hh));
        }
        {   // u=1: rl
            int base = ((8 + usq) * 64 + uhid) * 9;
            float zi = zbuf[base + 0] + zbuf[base + 4] + bD[0];
            float zf = zbuf[base + 1] + zbuf[base + 5] + bD[1];
            float zg = zbuf[base + 2] + zbuf[base + 6] + bD[2];
            float zo = zbuf[base + 3] + zbuf[base + 7] + bD[3];
            float ig = sigf(zi), fg = sigf(zf), gg = tanhfast(zg), og = sigf(zo);
            c1 = fg * c1 + ig * gg;
            float hn = og * tanhfast(c1);
            out[((size_t)(rowbase + usq) * II + s) * DH + 64 + uhid] = hn;
            unsigned short hh = f2bf(hn);
            int kk = 128 + uhid;
            int idx = (((kk >> 3) ^ usq) << 3) + (kk & 7);
            abuf[nb][1][usq * 192 + idx]       = hh;
            abuf[nb][1][(usq + 8) * 192 + idx] = f2bf(hn - bf2f(hh));
        }
        if (have_y) {
            int idx = (((yc4 >> 3) ^ ysq) << 3) + (yc4 & 7);
            short4s hv, lv;
#pragma unroll
            for (int j = 0; j < 4; ++j) {
                float x = ((const float*)&yv)[j];
                unsigned short hh = f2bf(x);
                hv[j] = (short)hh; lv[j] = (short)f2bf(x - bf2f(hh));
            }
            *(short4s*)&abuf[nb][yd][ysq * 192 + idx]       = hv;
            *(short4s*)&abuf[nb][yd][(ysq + 8) * 192 + idx] = lv;
        }
        __syncthreads();   // barrier 2
    }
}

// ========== fallback horiz (R5, in-place with stash) — verbatim ============
__global__ __launch_bounds__(512, 2)
void horiz_mfma4(const float* __restrict__ Wlr, const float* __restrict__ Ulr,
                 const float* __restrict__ blr,
                 const float* __restrict__ Wrl, const float* __restrict__ Url,
                 const float* __restrict__ brl,
                 float* __restrict__ out)
{
    __shared__ float stash[64][4][128];
    __shared__ unsigned short abuf[2][16 * 192];
    __shared__ float zbuf[8 * 64 * 9];

    const int tid  = threadIdx.x;
    const int w    = tid >> 6;
    const int l    = tid & 63;
    const int dirw = w >> 2;
    const int gt4  = w & 3;
    const int rowbase = blockIdx.x * 4;

    const float* Wp = dirw ? Wrl : Wlr;
    const float* Up = dirw ? Url : Ulr;
    short8 Bh[4][6], Bl[4][6];
#pragma unroll
    for (int nt = 0; nt < 4; ++nt) {
        const int gl = gt4 * 64 + nt * 16 + (l & 15);
#pragma unroll
        for (int kt = 0; kt < 6; ++kt) {
#pragma unroll
            for (int j = 0; j < 8; ++j) {
                int k = kt * 32 + ((l >> 4) << 3) + j;
                float vv = (k < DH) ? Wp[k * G4 + gl] : Up[(k - DH) * G4 + gl];
                unsigned short hh = f2bf(vv);
                Bh[nt][kt][j] = (short)hh;
                Bl[nt][kt][j] = (short)f2bf(vv - bf2f(hh));
            }
        }
    }

    const int udir = tid >> 8;
    const int up   = (tid >> 6) & 3;
    const int uhid = tid & 63;
    const int udp  = udir * 4 + up;
    const float* bp = udir ? brl : blr;
    const float bias_i = bp[0 * HID + uhid], bias_f = bp[1 * HID + uhid];
    const float bias_g = bp[2 * HID + uhid], bias_o = bp[3 * HID + uhid];
    float c_reg = 0.0f;
    const int orow = rowbase + up;

    const bool isload = (tid < 256);
    const int ldir = (tid >> 7) & 1;
    const int lp   = (tid >> 5) & 3;
    const int lc4  = (tid & 31) * 4;

    for (int i = tid; i < 16 * 64; i += 512) {
        int row = i >> 6, kk = 128 + (i & 63);
        abuf[0][(row * 192 + kk) ^ ((row & 7) << 3)] = 0;
    }
    if (isload) {
        int pos = ldir ? 127 : 0;
        float4 yv = *(const float4*)&out[((size_t)(rowbase + lp) * II + pos) * DH + lc4];
        int rowh = ldir * 4 + lp;
        short4s hv, lv;
#pragma unroll
        for (int j = 0; j < 4; ++j) {
            float x = ((const float*)&yv)[j];
            unsigned short hh = f2bf(x);
            hv[j] = (short)hh;
            lv[j] = (short)f2bf(x - bf2f(hh));
        }
        *(short4s*)&abuf[0][(rowh * 192 + lc4) ^ ((rowh & 7) << 3)] = hv;
        *(short4s*)&abuf[0][((rowh + 8) * 192 + lc4) ^ ((rowh & 7) << 3)] = lv;
        if (ldir == 0) *(float4*)&stash[0][lp][lc4] = yv;
    }
    __syncthreads();

    for (int s = 0; s < II; ++s) {
        const int buf = s & 1;
        float4 yv;
        bool have_y = false;
        if (isload && s < II - 1) {
            int pos = ldir ? (126 - s) : (s + 1);
            if (ldir && pos < 64)
                yv = *(const float4*)&stash[pos][lp][lc4];
            else
                yv = *(const float4*)&out[((size_t)(rowbase + lp) * II + pos) * DH + lc4];
            have_y = true;
        }

        short8 A[6];
#pragma unroll
        for (int kt = 0; kt < 6; ++kt) {
            int row = l & 15;
            int idx = (row * 192 + kt * 32 + ((l >> 4) << 3)) ^ ((row & 7) << 3);
            A[kt] = *(const short8*)&abuf[buf][idx];
        }

        const int lg = l >> 4;
#pragma unroll
        for (int nt = 0; nt < 4; ++nt) {
            f32x4 C = {0.f, 0.f, 0.f, 0.f};
#pragma unroll
            for (int kt = 0; kt < 6; ++kt)
                C = __builtin_amdgcn_mfma_f32_16x16x32_bf16(A[kt], Bh[nt][kt], C, 0, 0, 0);
#pragma unroll
            for (int kt = 0; kt < 6; ++kt)
                C = __builtin_amdgcn_mfma_f32_16x16x32_bf16(A[kt], Bl[nt][kt], C, 0, 0, 0);
            if ((lg & 1) == dirw) {
                int hid = nt * 16 + (l & 15);
                int part = lg >> 1;
#pragma unroll
                for (int r = 0; r < 4; ++r) {
                    int dp = dirw * 4 + r;
                    zbuf[(dp * 64 + hid) * 9 + part * 4 + gt4] = C[r];
                }
            }
        }
        __syncthreads();

        {
            int base = (udp * 64 + uhid) * 9;
            float zi = zbuf[base + 0] + zbuf[base + 4] + bias_i;
            float zf = zbuf[base + 1] + zbuf[base + 5] + bias_f;
            float zg = zbuf[base + 2] + zbuf[base + 6] + bias_g;
            float zo = zbuf[base + 3] + zbuf[base + 7] + bias_o;
            float ig = sigf(zi), fg = sigf(zf);
            float gg = tanhfast(zg), og = sigf(zo);
            c_reg = fg * c_reg + ig * gg;
            float hn = og * tanhfast(c_reg);
            out[((size_t)orow * II + s) * DH + udir * 64 + uhid] = hn;
            unsigned short hh = f2bf(hn);
            unsigned short hlo = f2bf(hn - bf2f(hh));
            int nb = buf ^ 1;
            abuf[nb][(udp * 192 + 128 + uhid) ^ ((udp & 7) << 3)] = hh;
            abuf[nb][((udp + 8) * 192 + 128 + uhid) ^ ((udp & 7) << 3)] = hlo;
        }

        if (have_y) {
            int nb = buf ^ 1;
            int rowh = ldir * 4 + lp;
            short4s hv, lv;
#pragma unroll
            for (int j = 0; j < 4; ++j) {
                float x = ((const float*)&yv)[j];
                unsigned short hh = f2bf(x);
                hv[j] = (short)hh;
                lv[j] = (short)f2bf(x - bf2f(hh));
            }
            *(short4s*)&abuf[nb][(rowh * 192 + lc4) ^ ((rowh & 7) << 3)] = hv;
            *(short4s*)&abuf[nb][((rowh + 8) * 192 + lc4) ^ ((rowh & 7) << 3)] = lv;
            if (ldir == 0 && (s + 1) < 64) *(float4*)&stash[s + 1][lp][lc4] = yv;
        }
        __syncthreads();
    }
}

extern "C" void kernel_launch(void* const* d_in, const int* in_sizes, int n_in,
                              void* d_out, int out_size, void* d_ws, size_t ws_size,
                              hipStream_t stream)
{
    const float* inp = (const float*)d_in[0];
    const float* Wud = (const float*)d_in[1];
    const float* Uud = (const float*)d_in[2];
    const float* bud = (const float*)d_in[3];
    const float* Wdu = (const float*)d_in[4];
    const float* Udu = (const float*)d_in[5];
    const float* bdu = (const float*)d_in[6];
    const float* Wlr = (const float*)d_in[7];
    const float* Ulr = (const float*)d_in[8];
    const float* blr = (const float*)d_in[9];
    const float* Wrl = (const float*)d_in[10];
    const float* Url = (const float*)d_in[11];
    const float* brl = (const float*)d_in[12];
    float* out = (float*)d_out;

    const size_t vbytes = (size_t)2048 * 128 * 128 * 4;   // 134 MB
    const bool use_ws = (ws_size >= vbytes);
    float* v = use_ws ? (float*)d_ws : out;

    vert_mfma<<<256, 512, 0, stream>>>(inp, Wud, Uud, bud, Wdu, Udu, bdu, v);
    if (use_ws)
        horiz_mfma8<<<256, 512, 0, stream>>>(Wlr, Ulr, blr, Wrl, Url, brl, v, out);
    else
        horiz_mfma4<<<512, 512, 0, stream>>>(Wlr, Ulr, blr, Wrl, Url, brl, out);
}